// Round 15
// baseline (56.021 us; speedup 1.0000x reference)
//
#include <hip/hip_runtime.h>
#include <math.h>

#define NB   8
#define SEQ  2048
#define EMB  8
#define NH   4
#define NFF  2048
#define NTOK (NB*SEQ)          // 16384
#define LNEPS 1e-5f

typedef float v2f __attribute__((ext_vector_type(2)));

__device__ __forceinline__ float fexp2(float x) {
#if __has_builtin(__builtin_amdgcn_exp2f)
    return __builtin_amdgcn_exp2f(x);       // raw v_exp_f32 (~1 ulp)
#else
    return exp2f(x);
#endif
}

__device__ __forceinline__ float dot8(const float4& a, const float4& b,
                                      const float4& c, const float4& d) {
    return a.x*b.x + a.y*b.y + a.z*b.z + a.w*b.w
         + c.x*d.x + c.y*d.y + c.z*d.z + c.w*d.w;
}

// ---------------------------------------------------------------------------
// projH[(b*4+h)][s][2] = (x @ Wp^T) head-major, and W2T[f][e] = W2[e][f]
// ---------------------------------------------------------------------------
__global__ __launch_bounds__(128) void k_prep(const float* __restrict__ x,
                                              const float* __restrict__ Wp,
                                              const float* __restrict__ W2,
                                              float* __restrict__ projH,
                                              float* __restrict__ w2t) {
    int t = blockIdx.x * 128 + threadIdx.x;
    if (t < NTOK) {
        int b = t >> 11, s = t & (SEQ - 1);
        const float4* xr = (const float4*)(x + (size_t)t * EMB);
        float4 xa = xr[0], xb = xr[1];
        float o[8];
#pragma unroll
        for (int e = 0; e < 8; ++e) {
            const float4* wr = (const float4*)(Wp + e * EMB);
            o[e] = dot8(xa, wr[0], xb, wr[1]);
        }
#pragma unroll
        for (int h = 0; h < 4; ++h) {
            *(float2*)(projH + ((size_t)(b * 4 + h) * SEQ + s) * 2) =
                make_float2(o[2 * h], o[2 * h + 1]);
        }
    }
    if (t < NFF) {
        float o[8];
#pragma unroll
        for (int e = 0; e < 8; ++e) o[e] = W2[e * NFF + t];
        float4* wr = (float4*)(w2t + (size_t)t * EMB);
        wr[0] = make_float4(o[0], o[1], o[2], o[3]);
        wr[1] = make_float4(o[4], o[5], o[6], o[7]);
    }
}

// ---------------------------------------------------------------------------
// attention v4 (R14-proven: log2-domain staging, single v_exp_f32/key).
// ---------------------------------------------------------------------------
#define QCA 64
__global__ __launch_bounds__(256) void k_attn(const float* __restrict__ projH,
                                              float* __restrict__ ctx) {
    __shared__ float Kx[SEQ];               // 8 KB  (pre-scaled by C)
    __shared__ float Ky[SEQ];               // 8 KB
    __shared__ float red[3][8][QCA];        // 6 KB

    int bid = blockIdx.x;
    int qc  = bid & 31;                     // 32 query chunks of 64
    int bh  = bid >> 5;                     // (b*4+h)

    const float C   = 1.01001959058f;       // sqrt(log2(e)/sqrt(2))
    const float RC  = 0.99008003302f;       // 1/C
    const float4* gsr = (const float4*)(projH + (size_t)bh * SEQ * 2);
#pragma unroll
    for (int ii = 0; ii < 4; ++ii) {
        int i = threadIdx.x + 256 * ii;
        float4 v = gsr[i];                  // keys 2i,2i+1: (x0,y0,x1,y1)
        *(float2*)&Kx[2 * i] = make_float2(v.x * C, v.z * C);
        *(float2*)&Ky[2 * i] = make_float2(v.y * C, v.w * C);
    }
    __syncthreads();

    int qg  = threadIdx.x & 31;             // 32 query groups of 2
    int sub = threadIdx.x >> 5;             // 8 key subranges of 256

    int q0 = qc * QCA + qg * 2;
    float qxa = Kx[q0],     qya = Ky[q0];       // already x C
    float qxb = Kx[q0 + 1], qyb = Ky[q0 + 1];
    v2f qx2a = {qxa, qxa}, qy2a = {qya, qya};
    v2f qx2b = {qxb, qxb}, qy2b = {qyb, qyb};

    v2f lA = {0.f, 0.f}, axA = {0.f, 0.f}, ayA = {0.f, 0.f};
    v2f lB = {0.f, 0.f}, axB = {0.f, 0.f}, ayB = {0.f, 0.f};

    const float4* Kx4 = (const float4*)Kx;
    const float4* Ky4 = (const float4*)Ky;
    int j04 = sub * 64;                     // 256 keys = 64 float4
#pragma unroll 2
    for (int jj = 0; jj < 64; ++jj) {
        float4 kx = Kx4[j04 + jj];          // broadcast reads: no conflicts
        float4 ky = Ky4[j04 + jj];
        v2f k0 = {kx.x, kx.y}, k1 = {kx.z, kx.w};
        v2f m0 = {ky.x, ky.y}, m1 = {ky.z, ky.w};

        v2f s0a = qx2a * k0 + qy2a * m0;    // pk mul/fma, log2-domain
        v2f s1a = qx2a * k1 + qy2a * m1;
        v2f s0b = qx2b * k0 + qy2b * m0;
        v2f s1b = qx2b * k1 + qy2b * m1;

        v2f p0a, p1a, p0b, p1b;
        p0a.x = fexp2(s0a.x); p0a.y = fexp2(s0a.y);
        p1a.x = fexp2(s1a.x); p1a.y = fexp2(s1a.y);
        p0b.x = fexp2(s0b.x); p0b.y = fexp2(s0b.y);
        p1b.x = fexp2(s1b.x); p1b.y = fexp2(s1b.y);

        lA  += p0a;            lB  += p0b;
        axA += p0a * k0;       axB += p0b * k0;
        ayA += p0a * m0;       ayB += p0b * m0;
        lA  += p1a;            lB  += p1b;
        axA += p1a * k1;       axB += p1b * k1;
        ayA += p1a * m1;       ayB += p1b * m1;
    }
    red[0][sub][qg * 2]     = lA.x + lA.y;
    red[1][sub][qg * 2]     = axA.x + axA.y;
    red[2][sub][qg * 2]     = ayA.x + ayA.y;
    red[0][sub][qg * 2 + 1] = lB.x + lB.y;
    red[1][sub][qg * 2 + 1] = axB.x + axB.y;
    red[2][sub][qg * 2 + 1] = ayB.x + ayB.y;
    __syncthreads();

    if (threadIdx.x < QCA) {
        float L = 0.f, A0 = 0.f, A1 = 0.f;
#pragma unroll
        for (int s = 0; s < 8; ++s) {
            L  += red[0][s][threadIdx.x];
            A0 += red[1][s][threadIdx.x];
            A1 += red[2][s][threadIdx.x];
        }
        float inv = RC / L;                 // undo the C on staged k
        int b = bh >> 2, h = bh & 3;
        int qglob = qc * QCA + threadIdx.x;
        *(float2*)(ctx + ((size_t)b * SEQ + qglob) * EMB + 2 * h) =
            make_float2(A0 * inv, A1 * inv);
    }
}

// ---------------------------------------------------------------------------
// FUSED post+FFN v7: W STAGED THROUGH LDS.  512 threads, TB=32, grid=512.
// Loop over 4 chunks of 512 f-rows: stage W1/w2t/bb1 chunk via dense
// coalesced float4 loads (latency-hidable stream; ~2us total), then compute
// entirely from LDS.  Compute mapping (contig-in-wave): wave wv covers
// local rows [wv*64, wv*64+64); per iter the 8 sw groups read 8 consecutive
// rows (32B apart -> 2-addr/bank-pair = conflict-free).  tg=tid&7:
// 4 tokens/thread.  In-wave shfl reduce over sw, cross-wave LDS reduce,
// LN2 via 8-lane shuffles.
// ---------------------------------------------------------------------------
#define TB3   32                // tokens per block
#define FCHNK 512               // f rows per staged chunk
__global__ __launch_bounds__(512) void k_ffn4(const float* __restrict__ ctx,
                                              const float* __restrict__ x,
                                              const float* __restrict__ Wo,
                                              const float* __restrict__ g1,
                                              const float* __restrict__ b1,
                                              const float* __restrict__ W1,
                                              const float* __restrict__ bb1,
                                              const float* __restrict__ w2t,
                                              const float* __restrict__ bb2,
                                              const float* __restrict__ g2,
                                              const float* __restrict__ b2,
                                              float* __restrict__ out) {
    __shared__ float Ws1[FCHNK][EMB];       // 16 KB
    __shared__ float Ws2[FCHNK][EMB];       // 16 KB
    __shared__ float bs[FCHNK];             // 2 KB
    __shared__ float q_lds[TB3][8];         // 1 KB
    __shared__ float x1_lds[TB3][8];        // 1 KB
    __shared__ float red[8][TB3][8];        // 8 KB

    int tid = threadIdx.x;

    // ---- prologue: post-attention for this block's 32 tokens (256 lanes) ----
    if (tid < TB3 * 8) {
        int tl = tid >> 3, e = tid & 7;
        int tok = blockIdx.x * TB3 + tl;
        const float4* cr = (const float4*)(ctx + (size_t)tok * EMB);
        float4 ca = cr[0], cb = cr[1];
        const float4* wr = (const float4*)(Wo + e * EMB);
        float ao = dot8(ca, wr[0], cb, wr[1]);
        float y = x[(size_t)tok * EMB + e] + ao;

        float s8 = y;
        s8 += __shfl_xor(s8, 1);
        s8 += __shfl_xor(s8, 2);
        s8 += __shfl_xor(s8, 4);
        float mu = s8 * 0.125f;
        float d  = y - mu;
        float vs = d * d;
        vs += __shfl_xor(vs, 1);
        vs += __shfl_xor(vs, 2);
        vs += __shfl_xor(vs, 4);
        float r = rsqrtf(vs * 0.125f + LNEPS);
        float v = d * r * g1[e] + b1[e];
        x1_lds[tl][e] = v;

        float p = __cosf(v);
        float t1 = __shfl_up(p, 1, 8); p = (e >= 1) ? p * t1 : p;
        float t2 = __shfl_up(p, 2, 8); p = (e >= 2) ? p * t2 : p;
        float t4 = __shfl_up(p, 4, 8); p = (e >= 4) ? p * t4 : p;
        q_lds[tl][e] = p;
    }
    __syncthreads();

    int tg = tid & 7;                       // 8 token groups x 4 tokens
    int sw = (tid >> 3) & 7;                // sub-in-wave (lane bits 3-5)
    int wv = tid >> 6;                      // wave 0..7
    int tl0 = tg * 4;

    float4 qa[4], qb[4];
#pragma unroll
    for (int k = 0; k < 4; ++k) {
        qa[k] = *(const float4*)&q_lds[tl0 + k][0];
        qb[k] = *(const float4*)&q_lds[tl0 + k][4];
    }

    float acc[4][8];
#pragma unroll
    for (int k = 0; k < 4; ++k)
#pragma unroll
        for (int e = 0; e < 8; ++e) acc[k][e] = 0.f;

    // ---- 4 chunks of 512 f rows, staged through LDS ----
    for (int c = 0; c < NFF / FCHNK; ++c) {
        const float4* gW1 = (const float4*)(W1 + (size_t)c * FCHNK * EMB);
        const float4* gW2 = (const float4*)(w2t + (size_t)c * FCHNK * EMB);
        float4* sW1 = (float4*)Ws1;
        float4* sW2 = (float4*)Ws2;
#pragma unroll
        for (int i = 0; i < 2; ++i) {       // 1024 float4 per array
            sW1[tid + 512 * i] = gW1[tid + 512 * i];
            sW2[tid + 512 * i] = gW2[tid + 512 * i];
        }
        bs[tid] = bb1[c * FCHNK + tid];
        __syncthreads();

        int fb = wv * 64 + sw;              // wave covers 64 consecutive rows
#pragma unroll 2
        for (int i = 0; i < 8; ++i) {
            int fl = fb + i * 8;            // 8 consecutive rows per wave instr
            float4 wa = *(const float4*)&Ws1[fl][0];
            float4 wb = *(const float4*)&Ws1[fl][4];
            float bias = bs[fl];
            float4 va = *(const float4*)&Ws2[fl][0];
            float4 vb = *(const float4*)&Ws2[fl][4];
#pragma unroll
            for (int k = 0; k < 4; ++k) {
                float hv = fmaxf(dot8(qa[k], wa, qb[k], wb) + bias, 0.f);
                acc[k][0] = fmaf(hv, va.x, acc[k][0]);
                acc[k][1] = fmaf(hv, va.y, acc[k][1]);
                acc[k][2] = fmaf(hv, va.z, acc[k][2]);
                acc[k][3] = fmaf(hv, va.w, acc[k][3]);
                acc[k][4] = fmaf(hv, vb.x, acc[k][4]);
                acc[k][5] = fmaf(hv, vb.y, acc[k][5]);
                acc[k][6] = fmaf(hv, vb.z, acc[k][6]);
                acc[k][7] = fmaf(hv, vb.w, acc[k][7]);
            }
        }
        __syncthreads();                    // before restaging
    }

    // in-wave reduce across the 8 sw groups (lane bits 3..5)
#pragma unroll
    for (int k = 0; k < 4; ++k)
#pragma unroll
        for (int e = 0; e < 8; ++e) {
            float v = acc[k][e];
            v += __shfl_xor(v, 8);
            v += __shfl_xor(v, 16);
            v += __shfl_xor(v, 32);
            acc[k][e] = v;
        }
    if (sw == 0) {                          // one sub-group per wave writes
#pragma unroll
        for (int k = 0; k < 4; ++k) {
            float4* d0 = (float4*)&red[wv][tl0 + k][0];
            d0[0] = make_float4(acc[k][0], acc[k][1], acc[k][2], acc[k][3]);
            d0[1] = make_float4(acc[k][4], acc[k][5], acc[k][6], acc[k][7]);
        }
    }
    __syncthreads();

    // ---- cross-wave reduce + LN2 (256 lanes = 32 tok x 8 e) ----
    if (tid < TB3 * 8) {
        int rtok = tid >> 3, re = tid & 7;
        float v = 0.f;
#pragma unroll
        for (int w = 0; w < 8; ++w) v += red[w][rtok][re];
        int tok = blockIdx.x * TB3 + rtok;
        v += bb2[re] + x1_lds[rtok][re];

        float s8 = v;
        s8 += __shfl_xor(s8, 1);
        s8 += __shfl_xor(s8, 2);
        s8 += __shfl_xor(s8, 4);
        float mu = s8 * 0.125f;
        float d  = v - mu;
        float vs = d * d;
        vs += __shfl_xor(vs, 1);
        vs += __shfl_xor(vs, 2);
        vs += __shfl_xor(vs, 4);
        float r = rsqrtf(vs * 0.125f + LNEPS);
        out[(size_t)tok * EMB + re] = d * r * g2[re] + b2[re];
    }
}

// ---------------------------------------------------------------------------
extern "C" void kernel_launch(void* const* d_in, const int* in_sizes, int n_in,
                              void* d_out, int out_size, void* d_ws, size_t ws_size,
                              hipStream_t stream) {
    const float* x   = (const float*)d_in[0];
    const float* Wp  = (const float*)d_in[1];
    const float* Wo  = (const float*)d_in[2];
    const float* g1  = (const float*)d_in[3];
    const float* b1  = (const float*)d_in[4];
    const float* W1  = (const float*)d_in[5];
    const float* bb1 = (const float*)d_in[6];
    const float* W2  = (const float*)d_in[7];
    const float* bb2 = (const float*)d_in[8];
    const float* g2  = (const float*)d_in[9];
    const float* b2  = (const float*)d_in[10];
    float* out = (float*)d_out;

    float* ws    = (float*)d_ws;
    float* projH = ws;                // 131072 f32 (head-major)
    float* ctx   = ws + 131072;       // 131072 f32
    float* w2t   = ws + 262144;       // 16384 f32

    hipLaunchKernelGGL(k_prep, dim3(NTOK / 128), dim3(128), 0, stream,
                       x, Wp, W2, projH, w2t);
    hipLaunchKernelGGL(k_attn, dim3((NB * NH) * (SEQ / QCA)), dim3(256), 0, stream,
                       projH, ctx);
    hipLaunchKernelGGL(k_ffn4, dim3(NTOK / TB3), dim3(512), 0, stream,
                       ctx, x, Wo, g1, b1, W1, bb1, w2t, bb2, g2, b2, out);
}

// Round 16
// 53.945 us; speedup vs baseline: 1.0385x; 1.0385x over previous
//
#include <hip/hip_runtime.h>
#include <math.h>

#define NB   8
#define SEQ  2048
#define EMB  8
#define NH   4
#define NFF  2048
#define NTOK (NB*SEQ)          // 16384
#define LNEPS 1e-5f

typedef float v2f __attribute__((ext_vector_type(2)));

__device__ __forceinline__ float fexp2(float x) {
#if __has_builtin(__builtin_amdgcn_exp2f)
    return __builtin_amdgcn_exp2f(x);       // raw v_exp_f32 (~1 ulp)
#else
    return exp2f(x);
#endif
}

__device__ __forceinline__ float dot8(const float4& a, const float4& b,
                                      const float4& c, const float4& d) {
    return a.x*b.x + a.y*b.y + a.z*b.z + a.w*b.w
         + c.x*d.x + c.y*d.y + c.z*d.z + c.w*d.w;
}

// ---------------------------------------------------------------------------
// projH[(b*4+h)][s][2] = (x @ Wp^T) head-major, and W2T[f][e] = W2[e][f]
// ---------------------------------------------------------------------------
__global__ __launch_bounds__(128) void k_prep(const float* __restrict__ x,
                                              const float* __restrict__ Wp,
                                              const float* __restrict__ W2,
                                              float* __restrict__ projH,
                                              float* __restrict__ w2t) {
    int t = blockIdx.x * 128 + threadIdx.x;
    if (t < NTOK) {
        int b = t >> 11, s = t & (SEQ - 1);
        const float4* xr = (const float4*)(x + (size_t)t * EMB);
        float4 xa = xr[0], xb = xr[1];
        float o[8];
#pragma unroll
        for (int e = 0; e < 8; ++e) {
            const float4* wr = (const float4*)(Wp + e * EMB);
            o[e] = dot8(xa, wr[0], xb, wr[1]);
        }
#pragma unroll
        for (int h = 0; h < 4; ++h) {
            *(float2*)(projH + ((size_t)(b * 4 + h) * SEQ + s) * 2) =
                make_float2(o[2 * h], o[2 * h + 1]);
        }
    }
    if (t < NFF) {
        float o[8];
#pragma unroll
        for (int e = 0; e < 8; ++e) o[e] = W2[e * NFF + t];
        float4* wr = (float4*)(w2t + (size_t)t * EMB);
        wr[0] = make_float4(o[0], o[1], o[2], o[3]);
        wr[1] = make_float4(o[4], o[5], o[6], o[7]);
    }
}

// ---------------------------------------------------------------------------
// attention v5: 4 queries/thread (LDS reads per pair HALVED — the CU-shared
// LDS pipe is the measured bottleneck).  16 key-subranges x 128 keys,
// QCA=64, grid = 32bh x 32qc = 1024 (4 blocks/CU).  Log2-domain staging
// (R14-proven): k' = k*C, score' already log2, one v_exp_f32 per pair.
// ---------------------------------------------------------------------------
#define QCA 64
__global__ __launch_bounds__(256) void k_attn(const float* __restrict__ projH,
                                              float* __restrict__ ctx) {
    __shared__ float Kx[SEQ];               // 8 KB  (pre-scaled by C)
    __shared__ float Ky[SEQ];               // 8 KB
    __shared__ float red[3][16][QCA];       // 12 KB

    int bid = blockIdx.x;
    int qc  = bid & 31;                     // 32 query chunks of 64
    int bh  = bid >> 5;                     // (b*4+h)

    const float C   = 1.01001959058f;       // sqrt(log2(e)/sqrt(2))
    const float RC  = 0.99008003302f;       // 1/C
    const float4* gsr = (const float4*)(projH + (size_t)bh * SEQ * 2);
#pragma unroll
    for (int ii = 0; ii < 4; ++ii) {
        int i = threadIdx.x + 256 * ii;
        float4 v = gsr[i];                  // keys 2i,2i+1: (x0,y0,x1,y1)
        *(float2*)&Kx[2 * i] = make_float2(v.x * C, v.z * C);
        *(float2*)&Ky[2 * i] = make_float2(v.y * C, v.w * C);
    }
    __syncthreads();

    int qg  = threadIdx.x & 15;             // 16 query groups of 4
    int sub = threadIdx.x >> 4;             // 16 key subranges of 128

    int q0 = qc * QCA + qg * 4;
    v2f qx2[4], qy2[4], l[4], ax[4], ay[4];
#pragma unroll
    for (int u = 0; u < 4; ++u) {
        float qx = Kx[q0 + u], qy = Ky[q0 + u];   // already x C
        qx2[u] = (v2f){qx, qx};
        qy2[u] = (v2f){qy, qy};
        l[u]  = (v2f){0.f, 0.f};
        ax[u] = (v2f){0.f, 0.f};
        ay[u] = (v2f){0.f, 0.f};
    }

    const float4* Kx4 = (const float4*)Kx;
    const float4* Ky4 = (const float4*)Ky;
    int j04 = sub * 32;                     // 128 keys = 32 float4
#pragma unroll 2
    for (int jj = 0; jj < 32; ++jj) {
        float4 kx = Kx4[j04 + jj];          // 4 distinct addrs/wave: broadcast
        float4 ky = Ky4[j04 + jj];
        v2f k0 = {kx.x, kx.y}, k1 = {kx.z, kx.w};
        v2f m0 = {ky.x, ky.y}, m1 = {ky.z, ky.w};
#pragma unroll
        for (int u = 0; u < 4; ++u) {
            v2f s0 = qx2[u] * k0 + qy2[u] * m0;   // pk mul/fma, log2-domain
            v2f s1 = qx2[u] * k1 + qy2[u] * m1;
            v2f p0, p1;
            p0.x = fexp2(s0.x); p0.y = fexp2(s0.y);
            p1.x = fexp2(s1.x); p1.y = fexp2(s1.y);
            l[u]  += p0;        l[u]  += p1;
            ax[u] += p0 * k0;   ax[u] += p1 * k1;
            ay[u] += p0 * m0;   ay[u] += p1 * m1;
        }
    }
#pragma unroll
    for (int u = 0; u < 4; ++u) {
        red[0][sub][qg * 4 + u] = l[u].x + l[u].y;
        red[1][sub][qg * 4 + u] = ax[u].x + ax[u].y;
        red[2][sub][qg * 4 + u] = ay[u].x + ay[u].y;
    }
    __syncthreads();

    if (threadIdx.x < QCA) {
        float L = 0.f, A0 = 0.f, A1 = 0.f;
#pragma unroll
        for (int s = 0; s < 16; ++s) {
            L  += red[0][s][threadIdx.x];
            A0 += red[1][s][threadIdx.x];
            A1 += red[2][s][threadIdx.x];
        }
        float inv = RC / L;                 // undo the C on staged k
        int b = bh >> 2, h = bh & 3;
        int qglob = qc * QCA + threadIdx.x;
        *(float2*)(ctx + ((size_t)b * SEQ + qglob) * EMB + 2 * h) =
            make_float2(A0 * inv, A1 * inv);
    }
}

// ---------------------------------------------------------------------------
// FUSED post+FFN v8: 8 TOKENS/THREAD (VMEM instrs per pair halved).
// 512 threads, TB=64 tokens/block, grid=256 (1 block/CU exact).
// Lane: tg = tid&7 (8 groups x 8 tokens), fslot = lane bits 3-5,
// wv = tid>>6.  f rows: thread walks 32 CONSECUTIVE rows starting
// (wv*8+fslot)*32 (L1 line reuse x4, R10-proven pattern).  In-wave shfl
// reduce over fslot (bits 3-5, unchanged), cross-wave LDS reduce, LN2 via
// 8-lane shuffles.  Prologue uses all 512 lanes (64 tok x 8 e).
// ---------------------------------------------------------------------------
#define TB3  64                 // tokens per block
#define FCH3 32                 // f rows per thread
__global__ __launch_bounds__(512) void k_ffn5(const float* __restrict__ ctx,
                                              const float* __restrict__ x,
                                              const float* __restrict__ Wo,
                                              const float* __restrict__ g1,
                                              const float* __restrict__ b1,
                                              const float* __restrict__ W1,
                                              const float* __restrict__ bb1,
                                              const float* __restrict__ w2t,
                                              const float* __restrict__ bb2,
                                              const float* __restrict__ g2,
                                              const float* __restrict__ b2,
                                              float* __restrict__ out) {
    __shared__ float q_lds[TB3][8];         // 2 KB
    __shared__ float x1_lds[TB3][8];        // 2 KB
    __shared__ float red[8][TB3][8];        // 16 KB: per-wave partials

    int tid = threadIdx.x;

    // ---- prologue: post-attention for this block's 64 tokens (512 lanes) ----
    {
        int tl = tid >> 3, e = tid & 7;
        int tok = blockIdx.x * TB3 + tl;
        const float4* cr = (const float4*)(ctx + (size_t)tok * EMB);
        float4 ca = cr[0], cb = cr[1];      // broadcast across the 8 lanes
        const float4* wr = (const float4*)(Wo + e * EMB);
        float ao = dot8(ca, wr[0], cb, wr[1]);
        float y = x[(size_t)tok * EMB + e] + ao;

        float s8 = y;
        s8 += __shfl_xor(s8, 1);
        s8 += __shfl_xor(s8, 2);
        s8 += __shfl_xor(s8, 4);
        float mu = s8 * 0.125f;
        float d  = y - mu;
        float vs = d * d;
        vs += __shfl_xor(vs, 1);
        vs += __shfl_xor(vs, 2);
        vs += __shfl_xor(vs, 4);
        float r = rsqrtf(vs * 0.125f + LNEPS);
        float v = d * r * g1[e] + b1[e];
        x1_lds[tl][e] = v;

        float p = __cosf(v);
        float t1 = __shfl_up(p, 1, 8); p = (e >= 1) ? p * t1 : p;
        float t2 = __shfl_up(p, 2, 8); p = (e >= 2) ? p * t2 : p;
        float t4 = __shfl_up(p, 4, 8); p = (e >= 4) ? p * t4 : p;
        q_lds[tl][e] = p;
    }
    __syncthreads();

    // ---- main FFN loop: 8 tokens x 32 sequential f rows per thread ----
    int tg    = tid & 7;                    // 8 token groups x 8 tokens
    int fslot = (tid >> 3) & 7;             // lane bits 3-5
    int wv    = tid >> 6;                   // wave 0..7
    int tl0   = tg * 8;

    float4 qa[8], qb[8];
#pragma unroll
    for (int k = 0; k < 8; ++k) {
        qa[k] = *(const float4*)&q_lds[tl0 + k][0];   // 8-lane broadcast
        qb[k] = *(const float4*)&q_lds[tl0 + k][4];
    }

    float acc[8][8];
#pragma unroll
    for (int k = 0; k < 8; ++k)
#pragma unroll
        for (int e = 0; e < 8; ++e) acc[k][e] = 0.f;

    int f0 = (wv * 8 + fslot) * FCH3;       // 32 consecutive rows per thread
#pragma unroll 2
    for (int i = 0; i < FCH3; ++i) {
        int f = f0 + i;                     // walks consecutive rows: L1 reuse
        const float4* w1r = (const float4*)(W1 + (size_t)f * EMB);
        float4 wa = w1r[0], wb = w1r[1];
        float bias = bb1[f];
        const float4* w2r = (const float4*)(w2t + (size_t)f * EMB);
        float4 va = w2r[0], vb = w2r[1];
#pragma unroll
        for (int k = 0; k < 8; ++k) {
            float hv = fmaxf(dot8(qa[k], wa, qb[k], wb) + bias, 0.f);
            acc[k][0] = fmaf(hv, va.x, acc[k][0]);
            acc[k][1] = fmaf(hv, va.y, acc[k][1]);
            acc[k][2] = fmaf(hv, va.z, acc[k][2]);
            acc[k][3] = fmaf(hv, va.w, acc[k][3]);
            acc[k][4] = fmaf(hv, vb.x, acc[k][4]);
            acc[k][5] = fmaf(hv, vb.y, acc[k][5]);
            acc[k][6] = fmaf(hv, vb.z, acc[k][6]);
            acc[k][7] = fmaf(hv, vb.w, acc[k][7]);
        }
    }

    // in-wave reduce across the 8 fslot groups (lane bits 3..5)
#pragma unroll
    for (int k = 0; k < 8; ++k)
#pragma unroll
        for (int e = 0; e < 8; ++e) {
            float v = acc[k][e];
            v += __shfl_xor(v, 8);
            v += __shfl_xor(v, 16);
            v += __shfl_xor(v, 32);
            acc[k][e] = v;
        }
    if (fslot == 0) {                       // lanes 0-7 of each wave write
#pragma unroll
        for (int k = 0; k < 8; ++k) {
            float4* d0 = (float4*)&red[wv][tl0 + k][0];
            d0[0] = make_float4(acc[k][0], acc[k][1], acc[k][2], acc[k][3]);
            d0[1] = make_float4(acc[k][4], acc[k][5], acc[k][6], acc[k][7]);
        }
    }
    __syncthreads();

    // ---- cross-wave reduce + LN2 (512 lanes = 64 tok x 8 e) ----
    {
        int rtok = tid >> 3, re = tid & 7;
        float v = 0.f;
#pragma unroll
        for (int w = 0; w < 8; ++w) v += red[w][rtok][re];
        int tok = blockIdx.x * TB3 + rtok;
        v += bb2[re] + x1_lds[rtok][re];

        float s8 = v;
        s8 += __shfl_xor(s8, 1);
        s8 += __shfl_xor(s8, 2);
        s8 += __shfl_xor(s8, 4);
        float mu = s8 * 0.125f;
        float d  = v - mu;
        float vs = d * d;
        vs += __shfl_xor(vs, 1);
        vs += __shfl_xor(vs, 2);
        vs += __shfl_xor(vs, 4);
        float r = rsqrtf(vs * 0.125f + LNEPS);
        out[(size_t)tok * EMB + re] = d * r * g2[re] + b2[re];
    }
}

// ---------------------------------------------------------------------------
extern "C" void kernel_launch(void* const* d_in, const int* in_sizes, int n_in,
                              void* d_out, int out_size, void* d_ws, size_t ws_size,
                              hipStream_t stream) {
    const float* x   = (const float*)d_in[0];
    const float* Wp  = (const float*)d_in[1];
    const float* Wo  = (const float*)d_in[2];
    const float* g1  = (const float*)d_in[3];
    const float* b1  = (const float*)d_in[4];
    const float* W1  = (const float*)d_in[5];
    const float* bb1 = (const float*)d_in[6];
    const float* W2  = (const float*)d_in[7];
    const float* bb2 = (const float*)d_in[8];
    const float* g2  = (const float*)d_in[9];
    const float* b2  = (const float*)d_in[10];
    float* out = (float*)d_out;

    float* ws    = (float*)d_ws;
    float* projH = ws;                // 131072 f32 (head-major)
    float* ctx   = ws + 131072;       // 131072 f32
    float* w2t   = ws + 262144;       // 16384 f32

    hipLaunchKernelGGL(k_prep, dim3(NTOK / 128), dim3(128), 0, stream,
                       x, Wp, W2, projH, w2t);
    hipLaunchKernelGGL(k_attn, dim3((NB * NH) * (SEQ / QCA)), dim3(256), 0, stream,
                       projH, ctx);
    hipLaunchKernelGGL(k_ffn5, dim3(NTOK / TB3), dim3(512), 0, stream,
                       ctx, x, Wo, g1, b1, W1, bb1, w2t, bb2, g2, b2, out);
}